// Round 3
// baseline (180.997 us; speedup 1.0000x reference)
//
#include <hip/hip_runtime.h>
#include <stdint.h>

#define NPTS        16384
#define BATCH       8
#define JC          512                     // refs per LDS chunk
#define NCHUNK      (NPTS / JC)             // 32
#define QPB         64                      // queries per block (2 waves * 32)
#define QBLKS       (NPTS / QPB)            // 256
#define CHAM_BLOCKS (BATCH * 2 * QBLKS)     // 4096
#define NOISE_N     (BATCH * NPTS * 3)      // 393216
#define NOISE_V4    (NOISE_N / 4)           // 98304
#define NPTS_TOT    (BATCH * NPTS)          // 131072
#define PACK_BLOCKS (NPTS_TOT / 256)        // 512

// workspace layout (bytes)
#define WS_PK_PRED  0
#define WS_PK_TARG  (8 * NPTS_TOT)

using halfx8 = __attribute__((ext_vector_type(8))) _Float16;
using f32x16 = __attribute__((ext_vector_type(16))) float;
using intx4  = __attribute__((ext_vector_type(4))) int;

__device__ __forceinline__ unsigned int f2h(float f) {
  union { _Float16 h; unsigned short s; } v; v.h = (_Float16)f; return v.s;
}
__device__ __forceinline__ float min3(float a, float b, float c) {
  return fminf(fminf(a, b), c);   // pattern-matched to v_min3_f32
}

// reduce 32 MFMA outputs + running min -> new running min (16 min3, optimal)
__device__ __forceinline__ float red33(float m, const f32x16& A, const f32x16& B) {
  float a0 = min3(A[0],  A[1],  A[2]);
  float a1 = min3(A[3],  A[4],  A[5]);
  float a2 = min3(A[6],  A[7],  A[8]);
  float a3 = min3(A[9],  A[10], A[11]);
  float a4 = min3(A[12], A[13], A[14]);
  float b0 = min3(B[0],  B[1],  B[2]);
  float b1 = min3(B[3],  B[4],  B[5]);
  float b2 = min3(B[6],  B[7],  B[8]);
  float b3 = min3(B[9],  B[10], B[11]);
  float b4 = min3(B[12], B[13], B[14]);
  float u0 = min3(a0, a1, a2);
  float u1 = min3(a3, a4, A[15]);
  float v0 = min3(b0, b1, b2);
  float v1 = min3(b3, b4, B[15]);
  float w0 = min3(u0, u1, v0);
  return min3(m, w0, v1);
}

// ---------------- fused pack (f32 xyz -> f16 {x,y,z,s}) + noise L1 ----------------
__global__ void pack_noise_kernel(const float* __restrict__ pred,
                                  const float* __restrict__ targ,
                                  const float4* __restrict__ na,
                                  const float4* __restrict__ nb,
                                  ushort4* __restrict__ pk_pred,
                                  ushort4* __restrict__ pk_targ,
                                  float* __restrict__ out) {
  int i = blockIdx.x * 256 + threadIdx.x;
  {
    float x = pred[3*i+0], y = pred[3*i+1], z = pred[3*i+2];
    float s = __builtin_fmaf(x, x, __builtin_fmaf(y, y, z*z));
    pk_pred[i] = make_ushort4((unsigned short)f2h(x), (unsigned short)f2h(y),
                              (unsigned short)f2h(z), (unsigned short)f2h(s));
  }
  {
    float x = targ[3*i+0], y = targ[3*i+1], z = targ[3*i+2];
    float s = __builtin_fmaf(x, x, __builtin_fmaf(y, y, z*z));
    pk_targ[i] = make_ushort4((unsigned short)f2h(x), (unsigned short)f2h(y),
                              (unsigned short)f2h(z), (unsigned short)f2h(s));
  }
  // noise L1 over float4-packed elements
  float sn = 0.f;
  if (i < NOISE_V4) {
    float4 pa = na[i], pb = nb[i];
    sn = fabsf(pa.x-pb.x) + fabsf(pa.y-pb.y) + fabsf(pa.z-pb.z) + fabsf(pa.w-pb.w);
  }
  for (int o = 1; o < 64; o <<= 1) sn += __shfl_xor(sn, o);
  __shared__ float ws4[4];
  int lane = threadIdx.x & 63, wv = threadIdx.x >> 6;
  if (lane == 0) ws4[wv] = sn;
  __syncthreads();
  if (threadIdx.x == 0)
    atomicAdd(out, (ws4[0] + ws4[1] + ws4[2] + ws4[3]) * (1.0f / NOISE_N));
}

// ---------------- chamfer main kernel ----------------
__global__ __launch_bounds__(128, 6)
void chamfer_kernel(const float* __restrict__ pred_f,
                    const float* __restrict__ targ_f,
                    const ushort4* __restrict__ pk_pred,
                    const ushort4* __restrict__ pk_targ,
                    float* __restrict__ out) {
  __shared__ __align__(16) ushort4 buf[2][JC];   // 8 KB double buffer
  __shared__ float wsum[2];

  const int tid  = threadIdx.x;
  const int lane = tid & 63;
  const int wv   = tid >> 6;
  const int col  = lane & 31;

  const int blk  = blockIdx.x;
  const int qblk = blk & (QBLKS - 1);
  const int bd   = blk >> 8;
  const int dir  = bd & 1;
  const int b    = bd >> 1;

  // dir 0: queries = pred (f32), refs = pk_targ; dir 1: swapped
  const float*   qf  = dir ? targ_f  : pred_f;
  const ushort4* ref = dir ? pk_pred : pk_targ;
  qf += (size_t)b * NPTS * 3; ref += (size_t)b * NPTS;

  // ---- query: pack 4 B fragments from raw f32 (no global pk needed) ----
  const int qg = qblk * QPB + wv * 32 + col;     // both lane halves load same q
  float qx = qf[3*qg+0], qy = qf[3*qg+1], qz = qf[3*qg+2];
  float rq = __builtin_fmaf(qx, qx, __builtin_fmaf(qy, qy, qz*qz));
  unsigned int lo = (f2h(-2.f*qy) << 16) | f2h(-2.f*qx);
  unsigned int hi = (0x3C00u << 16) | f2h(-2.f*qz);   // [nz, 1.0f16]
  const bool hh = (lane >= 32);

  // B[k][n]: lane l holds k = 8*(l>>5)+e (reg r packs e=2r,2r+1), n = l&31.
  // Variant v nonzero only at k=4v..4v+3 = [-2x,-2y,-2z,1]  -> selects one
  // of the 4 interleaved ref sets carried by the A quad.
  union BF { halfx8 v; unsigned int u[4]; };
  BF fb0, fb1, fb2, fb3;
  fb0.u[0] = hh ? 0u : lo; fb0.u[1] = hh ? 0u : hi; fb0.u[2] = 0u;           fb0.u[3] = 0u;
  fb1.u[0] = 0u;           fb1.u[1] = 0u;           fb1.u[2] = hh ? 0u : lo; fb1.u[3] = hh ? 0u : hi;
  fb2.u[0] = hh ? lo : 0u; fb2.u[1] = hh ? hi : 0u; fb2.u[2] = 0u;           fb2.u[3] = 0u;
  fb3.u[0] = 0u;           fb3.u[1] = 0u;           fb3.u[2] = hh ? lo : 0u; fb3.u[3] = hh ? hi : 0u;

  f32x16 czero = {0.f,0.f,0.f,0.f, 0.f,0.f,0.f,0.f, 0.f,0.f,0.f,0.f, 0.f,0.f,0.f,0.f};

  // stage chunk c into buf[pb]: wave wv covers bytes [wv*2048, wv*2048+2048)
  auto stage = [&](int c, int pb) {
    size_t go = (size_t)c * (JC * 8) + wv * 2048 + lane * 16;
    const char* g0 = (const char*)ref + go;
    char* l0 = (char*)&buf[pb][0] + wv * 2048 + lane * 16;
    __builtin_amdgcn_global_load_lds(
        (const __attribute__((address_space(1))) unsigned int*)(uintptr_t)g0,
        (__attribute__((address_space(3))) unsigned int*)(unsigned int)(uintptr_t)l0,
        16, 0, 0);
    __builtin_amdgcn_global_load_lds(
        (const __attribute__((address_space(1))) unsigned int*)(uintptr_t)(g0 + 1024),
        (__attribute__((address_space(3))) unsigned int*)(unsigned int)(uintptr_t)(l0 + 1024),
        16, 0, 0);
  };

  stage(0, 0);

  union AF { intx4 i; halfx8 h; };

  float m = 1e30f;
  for (int c = 0; c < NCHUNK; ++c) {
    const int pp = c & 1;
    __syncthreads();                           // drains stage(c)
    if (c + 1 < NCHUNK) stage(c + 1, pp ^ 1);  // flies during compute
    const char* base = (const char*)&buf[pp][0];
#pragma unroll
    for (int t = 0; t < 4; ++t) {
      // lane L holds refs (128t + 2L, 128t + 2L+1) as A[k] quad
      AF fa;
      fa.i = *(const intx4*)(base + t * 1024 + lane * 16);
      // pairs: only 2 accumulators live at a time (register footprint)
      f32x16 d0 = __builtin_amdgcn_mfma_f32_32x32x16_f16(fa.h, fb0.v, czero, 0, 0, 0);
      f32x16 d1 = __builtin_amdgcn_mfma_f32_32x32x16_f16(fa.h, fb1.v, czero, 0, 0, 0);
      m = red33(m, d0, d1);
      f32x16 d2 = __builtin_amdgcn_mfma_f32_32x32x16_f16(fa.h, fb2.v, czero, 0, 0, 0);
      f32x16 d3 = __builtin_amdgcn_mfma_f32_32x32x16_f16(fa.h, fb3.v, czero, 0, 0, 0);
      m = red33(m, d2, d3);
    }
  }

  // lanes l and l^32 cover complementary rows for the same query column
  m = fminf(m, __shfl_xor(m, 32));
  float dmin = fmaxf(rq + m, 0.f);
  float v = (lane < 32) ? dmin : 0.f;
  for (int o = 1; o < 32; o <<= 1) v += __shfl_xor(v, o);
  if (lane == 0) wsum[wv] = v;
  __syncthreads();
  if (tid == 0)
    atomicAdd(out, (wsum[0] + wsum[1]) * (0.1f / (float)NPTS_TOT));
}

extern "C" void kernel_launch(void* const* d_in, const int* in_sizes, int n_in,
                              void* d_out, int out_size, void* d_ws, size_t ws_size,
                              hipStream_t stream) {
  const float* pn = (const float*)d_in[0];
  const float* an = (const float*)d_in[1];
  const float* pp = (const float*)d_in[2];
  const float* tp = (const float*)d_in[3];

  char* ws = (char*)d_ws;
  ushort4* pk_pred = (ushort4*)(ws + WS_PK_PRED);
  ushort4* pk_targ = (ushort4*)(ws + WS_PK_TARG);
  float*   out     = (float*)d_out;

  hipMemsetAsync(d_out, 0, sizeof(float), stream);
  pack_noise_kernel<<<PACK_BLOCKS, 256, 0, stream>>>(pp, tp, (const float4*)pn,
                                                     (const float4*)an, pk_pred, pk_targ, out);
  chamfer_kernel<<<CHAM_BLOCKS, 128, 0, stream>>>(pp, tp, pk_pred, pk_targ, out);
}